// Round 6
// baseline (148.312 us; speedup 1.0000x reference)
//
#include <hip/hip_runtime.h>

// ---------------------------------------------------------------------------
// Per-batch dynamic conv stack + polynomial attention (f32).
//   feature (8,360) = mean(thumb,(2,3)) @ Wm + bm
//   conv_stack: residual + [3x conv3x3(SAME,leaky 0.2)] -> [5x conv1x1(leaky)]
//   attention:  out = y * (1 + prod_i(a*h + b*w + c*y + d)) per channel
// Outputs: x_out (8,3,512,512) then thumb_out (8,3,64,64), flat f32.
//
// R6: VGPR-quantum push. m69: waves/CU halve at vgpr={64,128,256}; R1-R5 all
// sat in the 128-reg step (72-100 VGPRs) -> 4 blocks/CU no matter the LDS.
// Changes vs R5:
//   * __launch_bounds__(256, 8): force <=64 VGPRs -> 8 blocks/CU (LDS 19.1KB
//     allows 8). Spill watch: WRITE_SIZE must stay ~25MB.
//   * residual re-read from global at epilogue (L2-hot) instead of 12 regs.
//   * lean windows: per (ich,row) read B(float4) + aw + cx scalars = exactly
//     the 6 used floats (was 3x float4 = 12), ~half the LDS-pipe cycles.
// ---------------------------------------------------------------------------

#define LEAKY(v) fmaxf((v), 0.2f * (v))

constexpr int STRD = 72;            // dwords per buffered row (cols -4..67)
constexpr int ROWS0 = 22;           // rows -3..18
constexpr int CHS  = ROWS0 * STRD;  // 1584 dwords per channel slab
constexpr int BUFSZ = 3 * CHS + 16; // + pad for right-edge overread

__global__ __launch_bounds__(256) void means_kernel(
    const float* __restrict__ thumb, float* __restrict__ ws)
{
    const int bc = blockIdx.x;               // b*3+c, 24 blocks
    const int tid = threadIdx.x;
    const float4* p = (const float4*)(thumb + (size_t)bc * 4096);
    float s = 0.f;
#pragma unroll
    for (int k = 0; k < 4; ++k) {
        float4 v = p[tid + k * 256];
        s += v.x + v.y + v.z + v.w;
    }
    __shared__ float red[256];
    red[tid] = s;
    __syncthreads();
    for (int off = 128; off > 0; off >>= 1) {
        if (tid < off) red[tid] += red[tid + off];
        __syncthreads();
    }
    if (tid == 0) ws[bc] = red[0] * (1.f / 4096.f);
}

__global__ __launch_bounds__(384) void fmm_kernel(
    const float* __restrict__ Wm, const float* __restrict__ bm,
    const float* __restrict__ ws, float* __restrict__ feat)
{
    const int b = blockIdx.x;                // 8 blocks
    const int f = threadIdx.x;
    if (f < 360) {
        const float m0 = ws[b * 3 + 0], m1 = ws[b * 3 + 1], m2 = ws[b * 3 + 2];
        feat[b * 360 + f] =
            fmaf(m0, Wm[f], fmaf(m1, Wm[360 + f], fmaf(m2, Wm[720 + f], bm[f])));
    }
}

// 3x3 conv over a strip of R output rows x 4 cols (gx..gx+3), all 3 och.
// Reads exactly the 6 needed floats per (ich,row): aw | B.xyzw | cx.
// gx may be -4 (aw clamped in-bounds; garbage feeds only discarded cols).
template<int R>
__device__ __forceinline__ void conv_rows(
    const float* __restrict__ buf, const float* __restrict__ fw,
    int r0, int gx, float4 acc[][3])
{
    const float b0 = fw[81], b1 = fw[82], b2 = fw[83];
#pragma unroll
    for (int j = 0; j < R; ++j) {
        acc[j][0] = make_float4(b0, b0, b0, b0);
        acc[j][1] = make_float4(b1, b1, b1, b1);
        acc[j][2] = make_float4(b2, b2, b2, b2);
    }
    const int awo = (gx < 0) ? 0 : gx + 3;   // col gx-1 (clamped at left halo)
#pragma unroll
    for (int ich = 0; ich < 3; ++ich) {
#pragma unroll
        for (int ri = 0; ri < R + 2; ++ri) {
            const int idx = ich * CHS + (r0 + 2 + ri) * STRD;
            const float aw = buf[idx + awo];
            const float4 B = *(const float4*)&buf[idx + gx + 4]; // cols gx..gx+3
            const float cx = buf[idx + gx + 8];                  // col gx+4
#pragma unroll
            for (int j = 0; j < R; ++j) {
                const int dy = ri - j;
                if (dy < 0 || dy > 2) continue;
#pragma unroll
                for (int oc = 0; oc < 3; ++oc) {
                    const float w0 = fw[oc * 27 + ich * 9 + dy * 3 + 0];
                    const float w1 = fw[oc * 27 + ich * 9 + dy * 3 + 1];
                    const float w2 = fw[oc * 27 + ich * 9 + dy * 3 + 2];
                    float4& a = acc[j][oc];
                    a.x = fmaf(aw,  w0, fmaf(B.x, w1, fmaf(B.y, w2, a.x)));
                    a.y = fmaf(B.x, w0, fmaf(B.y, w1, fmaf(B.z, w2, a.y)));
                    a.z = fmaf(B.y, w0, fmaf(B.z, w1, fmaf(B.w, w2, a.z)));
                    a.w = fmaf(B.z, w0, fmaf(B.w, w1, fmaf(cx,  w2, a.w)));
                }
            }
        }
    }
}

__global__ __launch_bounds__(256, 8) void conv_att_kernel(
    const float* __restrict__ x, const float* __restrict__ thumb,
    const float* __restrict__ feat, float* __restrict__ out)
{
    __shared__ float buf[BUFSZ];

    int id = blockIdx.x;
    const float* src; float* dst; int H, W, b, trow, tcol;
    if (id < 2048) {                 // big: 8 batches x (32 row x 8 col) tiles
        b = id >> 8; const int t = id & 255;
        H = 512; W = 512; trow = (t >> 3) * 16; tcol = (t & 7) * 64;
        src = x; dst = out;
    } else {                         // thumb: 8 batches x 4 row tiles
        const int i2 = id - 2048;
        b = i2 >> 2; trow = (i2 & 3) * 16; tcol = 0;
        H = 64; W = 64; src = thumb;
        dst = out + (size_t)8 * 3 * 512 * 512;
    }
    const float* fb = feat + b * 360;    // uniform -> scalar loads
    const int tid = threadIdx.x;

    // ---- stage0 load: 1188 float4 slots (3ch x 22 rows x 18 quads) ----
    const float* sbg = src + (size_t)b * 3 * H * W;
    for (int q = tid; q < 1188; q += 256) {
        const int c = q / 396;                 // 396 = 22*18
        const int rem = q - c * 396;
        const int mr = rem / 18;
        const int mq = rem - mr * 18;
        const int gr = trow + mr - 3;
        const int gc0 = tcol + 4 * mq - 4;
        const bool rok = (unsigned)gr < (unsigned)H;
        const float* gp = sbg + (size_t)c * H * W + (size_t)(rok ? gr : 0) * W;
        float4 v;
        if (rok && (unsigned)gc0 <= (unsigned)(W - 4)) {
            v = *(const float4*)&gp[gc0];      // interior fast path
        } else {
            v.x = (rok && (unsigned)(gc0 + 0) < (unsigned)W) ? gp[gc0 + 0] : 0.f;
            v.y = (rok && (unsigned)(gc0 + 1) < (unsigned)W) ? gp[gc0 + 1] : 0.f;
            v.z = (rok && (unsigned)(gc0 + 2) < (unsigned)W) ? gp[gc0 + 2] : 0.f;
            v.w = (rok && (unsigned)(gc0 + 3) < (unsigned)W) ? gp[gc0 + 3] : 0.f;
        }
        *(float4*)&buf[c * CHS + mr * STRD + 4 * mq] = v;
    }
    __syncthreads();

    // conv3/output mapping: 16 rows x 16 quad-groups, R=1
    const int s3 = tid >> 4;             // output row 0..15
    const int gx3 = 4 * (tid & 15);      // output col group

    // conv1: 10 strips (R=2, rows -2..17) x 18 groups = 180 units
    const bool act1 = tid < 180;
    const int s1 = tid / 18;
    const int gx1 = 4 * (tid - s1 * 18) - 4;
    float4 acc[2][3];
    if (act1) conv_rows<2>(buf, fb, 2 * s1 - 2, gx1, acc);
    __syncthreads();

    if (act1) {
        const int r0 = 2 * s1 - 2;
#pragma unroll
        for (int j = 0; j < 2; ++j)
#pragma unroll
            for (int oc = 0; oc < 3; ++oc) {
                float4 v = acc[j][oc];
                v.x = LEAKY(v.x); v.y = LEAKY(v.y); v.z = LEAKY(v.z); v.w = LEAKY(v.w);
                *(float4*)&buf[oc * CHS + (r0 + j + 3) * STRD + gx1 + 4] = v;
            }
    }
    __syncthreads();

    // conv2: 9 strips (R=2, rows -1..16) x 18 groups = 162 units (exact)
    const bool act2 = tid < 162;
    const int s2 = tid / 18;
    const int gx2 = 4 * (tid - s2 * 18) - 4;
    if (act2) conv_rows<2>(buf, fb + 84, 2 * s2 - 1, gx2, acc);
    __syncthreads();

    if (act2) {
        const int r0 = 2 * s2 - 1;
#pragma unroll
        for (int j = 0; j < 2; ++j)
#pragma unroll
            for (int oc = 0; oc < 3; ++oc) {
                float4 v = acc[j][oc];
                v.x = LEAKY(v.x); v.y = LEAKY(v.y); v.z = LEAKY(v.z); v.w = LEAKY(v.w);
                *(float4*)&buf[oc * CHS + (r0 + j + 3) * STRD + gx2 + 4] = v;
            }
    }
    __syncthreads();

    // ---- residual re-read from global (L2-hot; issued before conv3 math) ----
    const int gr = trow + s3;
    float4 res[3];
#pragma unroll
    for (int c = 0; c < 3; ++c)
        res[c] = *(const float4*)&sbg[((size_t)c * H + gr) * W + tcol + gx3];

    // conv3: rows 0..15, R=1, all 256 threads
    float4 y[1][3];
    conv_rows<1>(buf, fb + 168, s3, gx3, y);
    float4 y0 = y[0][0], y1 = y[0][1], y2 = y[0][2];
    y0.x = LEAKY(y0.x); y0.y = LEAKY(y0.y); y0.z = LEAKY(y0.z); y0.w = LEAKY(y0.w);
    y1.x = LEAKY(y1.x); y1.y = LEAKY(y1.y); y1.z = LEAKY(y1.z); y1.w = LEAKY(y1.w);
    y2.x = LEAKY(y2.x); y2.y = LEAKY(y2.y); y2.z = LEAKY(y2.z); y2.w = LEAKY(y2.w);

    // ---- 5x conv1x1 chain in registers ----
#pragma unroll
    for (int lay = 0; lay < 5; ++lay) {
        const float* fw = fb + 252 + lay * 12;
        const float w00 = fw[0], w01 = fw[1], w02 = fw[2];
        const float w10 = fw[3], w11 = fw[4], w12 = fw[5];
        const float w20 = fw[6], w21 = fw[7], w22 = fw[8];
        const float c0 = fw[9], c1 = fw[10], c2 = fw[11];
        float4 z0, z1, z2;
        z0.x = fmaf(y0.x, w00, fmaf(y1.x, w01, fmaf(y2.x, w02, c0)));
        z0.y = fmaf(y0.y, w00, fmaf(y1.y, w01, fmaf(y2.y, w02, c0)));
        z0.z = fmaf(y0.z, w00, fmaf(y1.z, w01, fmaf(y2.z, w02, c0)));
        z0.w = fmaf(y0.w, w00, fmaf(y1.w, w01, fmaf(y2.w, w02, c0)));
        z1.x = fmaf(y0.x, w10, fmaf(y1.x, w11, fmaf(y2.x, w12, c1)));
        z1.y = fmaf(y0.y, w10, fmaf(y1.y, w11, fmaf(y2.y, w12, c1)));
        z1.z = fmaf(y0.z, w10, fmaf(y1.z, w11, fmaf(y2.z, w12, c1)));
        z1.w = fmaf(y0.w, w10, fmaf(y1.w, w11, fmaf(y2.w, w12, c1)));
        z2.x = fmaf(y0.x, w20, fmaf(y1.x, w21, fmaf(y2.x, w22, c2)));
        z2.y = fmaf(y0.y, w20, fmaf(y1.y, w21, fmaf(y2.y, w22, c2)));
        z2.z = fmaf(y0.z, w20, fmaf(y1.z, w21, fmaf(y2.z, w22, c2)));
        z2.w = fmaf(y0.w, w20, fmaf(y1.w, w21, fmaf(y2.w, w22, c2)));
        y0.x = LEAKY(z0.x); y0.y = LEAKY(z0.y); y0.z = LEAKY(z0.z); y0.w = LEAKY(z0.w);
        y1.x = LEAKY(z1.x); y1.y = LEAKY(z1.y); y1.z = LEAKY(z1.z); y1.w = LEAKY(z1.w);
        y2.x = LEAKY(z2.x); y2.y = LEAKY(z2.y); y2.z = LEAKY(z2.z); y2.w = LEAKY(z2.w);
    }

    // ---- residual + attention + float4 store (1 row x 4 cols x 3 ch) ----
    const float invH = 1.f / (float)H;
    const float invW = 1.f / (float)W;
    const float h = (float)gr * invH;
    const float wbase = (float)(tcol + gx3) * invW;
    const float4 wv = make_float4(wbase, wbase + invW, wbase + 2.f * invW, wbase + 3.f * invW);
#pragma unroll
    for (int ch = 0; ch < 3; ++ch) {
        const float* fp = fb + 312 + ch * 16;
        const float pa0 = fp[0], pb0 = fp[1], pc0 = fp[2], pd0 = fp[3];
        const float pa1 = fp[4], pb1 = fp[5], pc1 = fp[6], pd1 = fp[7];
        const float pa2 = fp[8], pb2 = fp[9], pc2 = fp[10], pd2 = fp[11];
        const float pa3 = fp[12], pb3 = fp[13], pc3 = fp[14], pd3 = fp[15];
        const float4 yv = (ch == 0) ? y0 : (ch == 1) ? y1 : y2;
        float4 v;
        v.x = yv.x + res[ch].x;
        v.y = yv.y + res[ch].y;
        v.z = yv.z + res[ch].z;
        v.w = yv.w + res[ch].w;
        const float t0 = fmaf(pa0, h, pd0), t1 = fmaf(pa1, h, pd1);
        const float t2 = fmaf(pa2, h, pd2), t3 = fmaf(pa3, h, pd3);
        float4 o;
        float a0 = fmaf(pb0, wv.x, fmaf(pc0, v.x, t0));
        a0 *= fmaf(pb1, wv.x, fmaf(pc1, v.x, t1));
        a0 *= fmaf(pb2, wv.x, fmaf(pc2, v.x, t2));
        a0 *= fmaf(pb3, wv.x, fmaf(pc3, v.x, t3));
        o.x = v.x * (1.f + a0);
        float a1 = fmaf(pb0, wv.y, fmaf(pc0, v.y, t0));
        a1 *= fmaf(pb1, wv.y, fmaf(pc1, v.y, t1));
        a1 *= fmaf(pb2, wv.y, fmaf(pc2, v.y, t2));
        a1 *= fmaf(pb3, wv.y, fmaf(pc3, v.y, t3));
        o.y = v.y * (1.f + a1);
        float a2 = fmaf(pb0, wv.z, fmaf(pc0, v.z, t0));
        a2 *= fmaf(pb1, wv.z, fmaf(pc1, v.z, t1));
        a2 *= fmaf(pb2, wv.z, fmaf(pc2, v.z, t2));
        a2 *= fmaf(pb3, wv.z, fmaf(pc3, v.z, t3));
        o.z = v.z * (1.f + a2);
        float a3 = fmaf(pb0, wv.w, fmaf(pc0, v.w, t0));
        a3 *= fmaf(pb1, wv.w, fmaf(pc1, v.w, t1));
        a3 *= fmaf(pb2, wv.w, fmaf(pc2, v.w, t2));
        a3 *= fmaf(pb3, wv.w, fmaf(pc3, v.w, t3));
        o.w = v.w * (1.f + a3);
        *(float4*)&dst[((size_t)(b * 3 + ch) * H + gr) * W + tcol + gx3] = o;
    }
}

extern "C" void kernel_launch(void* const* d_in, const int* in_sizes, int n_in,
                              void* d_out, int out_size, void* d_ws, size_t ws_size,
                              hipStream_t stream) {
    const float* x = (const float*)d_in[0];       // (8,3,512,512)
    const float* thumb = (const float*)d_in[1];   // (8,3,64,64)
    const float* Wm = (const float*)d_in[2];      // (3,360)
    const float* bm = (const float*)d_in[3];      // (360,)
    float* out = (float*)d_out;
    float* means = (float*)d_ws;                  // 24 floats
    float* feat = (float*)d_ws + 64;              // (8,360)

    means_kernel<<<24, 256, 0, stream>>>(thumb, means);
    fmm_kernel<<<8, 384, 0, stream>>>(Wm, bm, means, feat);
    // 2048 big-image blocks + 32 thumb blocks
    conv_att_kernel<<<2080, 256, 0, stream>>>(x, thumb, feat, out);
}

// Round 7
// 118.946 us; speedup vs baseline: 1.2469x; 1.2469x over previous
//
#include <hip/hip_runtime.h>

// ---------------------------------------------------------------------------
// Per-batch dynamic conv stack + polynomial attention (f32).
//   feature (8,360) = mean(thumb,(2,3)) @ Wm + bm
//   conv_stack: residual + [3x conv3x3(SAME,leaky 0.2)] -> [5x conv1x1(leaky)]
//   attention:  out = y * (1 + prod_i(a*h + b*w + c*y + d)) per channel
// Outputs: x_out (8,3,512,512) then thumb_out (8,3,64,64), flat f32.
//
// R7: barrier-group split. R5 structure (in-place LDS, float4 windows,
// s_load weights) but 128-thread blocks on 8x64 tiles:
//   * VGPR ~72 -> 4 waves/SIMD (128-reg HW step, m69). 256-thr blocks gave
//     only 4 barrier domains/CU; 128-thr blocks give 8 -> barrier stalls
//     cover 2 waves while 14 run. LDS 12.2KB allows all 8.
//   * (128,4) bounds: allocator target 128 regs (R5's proven no-spill zone).
//     R6's (256,8) forced 32 regs -> 157MB scratch writes. Never again.
//   * conv1 108/128, conv2 90/128, conv3 128/128 thread utilization.
// ---------------------------------------------------------------------------

#define LEAKY(v) fmaxf((v), 0.2f * (v))

constexpr int STRD = 72;            // dwords per buffered row (cols -4..67)
constexpr int ROWS0 = 14;           // rows -3..10
constexpr int CHS  = ROWS0 * STRD;  // 1008 dwords per channel slab
constexpr int BUFSZ = 3 * CHS + 16; // + pad for right-edge overread (12.2KB)

__global__ __launch_bounds__(256) void means_kernel(
    const float* __restrict__ thumb, float* __restrict__ ws)
{
    const int bc = blockIdx.x;               // b*3+c, 24 blocks
    const int tid = threadIdx.x;
    const float4* p = (const float4*)(thumb + (size_t)bc * 4096);
    float s = 0.f;
#pragma unroll
    for (int k = 0; k < 4; ++k) {
        float4 v = p[tid + k * 256];
        s += v.x + v.y + v.z + v.w;
    }
    __shared__ float red[256];
    red[tid] = s;
    __syncthreads();
    for (int off = 128; off > 0; off >>= 1) {
        if (tid < off) red[tid] += red[tid + off];
        __syncthreads();
    }
    if (tid == 0) ws[bc] = red[0] * (1.f / 4096.f);
}

__global__ __launch_bounds__(384) void fmm_kernel(
    const float* __restrict__ Wm, const float* __restrict__ bm,
    const float* __restrict__ ws, float* __restrict__ feat)
{
    const int b = blockIdx.x;                // 8 blocks
    const int f = threadIdx.x;
    if (f < 360) {
        const float m0 = ws[b * 3 + 0], m1 = ws[b * 3 + 1], m2 = ws[b * 3 + 2];
        feat[b * 360 + f] =
            fmaf(m0, Wm[f], fmaf(m1, Wm[360 + f], fmaf(m2, Wm[720 + f], bm[f])));
    }
}

// 3x3 conv over a strip of R output rows x 4 cols (gx..gx+3), all 3 och.
// fw: 84 uniform weights; r0: first output row; gx: first col (multiple of 4,
// may be -4: left-edge A-clamp feeds only discarded outputs).
template<int R>
__device__ __forceinline__ void conv_rows(
    const float* __restrict__ buf, const float* __restrict__ fw,
    int r0, int gx, float4 acc[][3])
{
    const float b0 = fw[81], b1 = fw[82], b2 = fw[83];
#pragma unroll
    for (int j = 0; j < R; ++j) {
        acc[j][0] = make_float4(b0, b0, b0, b0);
        acc[j][1] = make_float4(b1, b1, b1, b1);
        acc[j][2] = make_float4(b2, b2, b2, b2);
    }
    const int gA = (gx < 0) ? 0 : gx;
#pragma unroll
    for (int ich = 0; ich < 3; ++ich) {
#pragma unroll
        for (int ri = 0; ri < R + 2; ++ri) {
            const int idx = ich * CHS + (r0 + 2 + ri) * STRD;
            const float4 A = *(const float4*)&buf[idx + gA];     // gx-4..gx-1
            const float4 B = *(const float4*)&buf[idx + gx + 4]; // gx..gx+3
            const float4 C = *(const float4*)&buf[idx + gx + 8]; // gx+4..gx+7
#pragma unroll
            for (int j = 0; j < R; ++j) {
                const int dy = ri - j;
                if (dy < 0 || dy > 2) continue;
#pragma unroll
                for (int oc = 0; oc < 3; ++oc) {
                    const float w0 = fw[oc * 27 + ich * 9 + dy * 3 + 0];
                    const float w1 = fw[oc * 27 + ich * 9 + dy * 3 + 1];
                    const float w2 = fw[oc * 27 + ich * 9 + dy * 3 + 2];
                    float4& a = acc[j][oc];
                    a.x = fmaf(A.w, w0, fmaf(B.x, w1, fmaf(B.y, w2, a.x)));
                    a.y = fmaf(B.x, w0, fmaf(B.y, w1, fmaf(B.z, w2, a.y)));
                    a.z = fmaf(B.y, w0, fmaf(B.z, w1, fmaf(B.w, w2, a.z)));
                    a.w = fmaf(B.z, w0, fmaf(B.w, w1, fmaf(C.x, w2, a.w)));
                }
            }
        }
    }
}

__global__ __launch_bounds__(128, 4) void conv_att_kernel(
    const float* __restrict__ x, const float* __restrict__ thumb,
    const float* __restrict__ feat, float* __restrict__ out)
{
    __shared__ float buf[BUFSZ];

    int id = blockIdx.x;
    const float* src; float* dst; int H, W, b, trow, tcol;
    if (id < 4096) {                 // big: 8 batches x (64 row x 8 col) tiles
        b = id >> 9; const int t = id & 511;
        H = 512; W = 512; trow = (t >> 3) * 8; tcol = (t & 7) * 64;
        src = x; dst = out;
    } else {                         // thumb: 8 batches x 8 row tiles
        const int i2 = id - 4096;
        b = i2 >> 3; trow = (i2 & 7) * 8; tcol = 0;
        H = 64; W = 64; src = thumb;
        dst = out + (size_t)8 * 3 * 512 * 512;
    }
    const float* fb = feat + b * 360;    // uniform -> scalar loads
    const int tid = threadIdx.x;

    // ---- stage0 load: 756 float4 slots (3ch x 14 rows x 18 quads) ----
    const float* sbg = src + (size_t)b * 3 * H * W;
    for (int q = tid; q < 756; q += 128) {
        const int c = q / 252;                 // 252 = 14*18
        const int rem = q - c * 252;
        const int mr = rem / 18;
        const int mq = rem - mr * 18;
        const int gr = trow + mr - 3;
        const int gc0 = tcol + 4 * mq - 4;
        const bool rok = (unsigned)gr < (unsigned)H;
        const float* gp = sbg + (size_t)c * H * W + (size_t)(rok ? gr : 0) * W;
        float4 v;
        if (rok && (unsigned)gc0 <= (unsigned)(W - 4)) {
            v = *(const float4*)&gp[gc0];      // interior fast path
        } else {
            v.x = (rok && (unsigned)(gc0 + 0) < (unsigned)W) ? gp[gc0 + 0] : 0.f;
            v.y = (rok && (unsigned)(gc0 + 1) < (unsigned)W) ? gp[gc0 + 1] : 0.f;
            v.z = (rok && (unsigned)(gc0 + 2) < (unsigned)W) ? gp[gc0 + 2] : 0.f;
            v.w = (rok && (unsigned)(gc0 + 3) < (unsigned)W) ? gp[gc0 + 3] : 0.f;
        }
        *(float4*)&buf[c * CHS + mr * STRD + 4 * mq] = v;
    }
    __syncthreads();

    // conv3/output mapping (also residual): 8 rows x 16 quad-groups, R=1
    const int s3 = tid >> 4;             // output row 0..7
    const int gx3 = 4 * (tid & 15);      // output col group

    // conv1: 6 strips (R=2, rows -2..9) x 18 groups = 108 units
    const bool act1 = tid < 108;
    const int s1 = tid / 18;
    const int gx1 = 4 * (tid - s1 * 18) - 4;
    float4 acc[2][3];
    if (act1) conv_rows<2>(buf, fb, 2 * s1 - 2, gx1, acc);

    // residual stash (stage0 center rows 3..10, read before overwrite)
    float4 res[3];
#pragma unroll
    for (int c = 0; c < 3; ++c)
        res[c] = *(const float4*)&buf[c * CHS + (s3 + 3) * STRD + gx3 + 4];
    __syncthreads();

    if (act1) {
        const int r0 = 2 * s1 - 2;
#pragma unroll
        for (int j = 0; j < 2; ++j)
#pragma unroll
            for (int oc = 0; oc < 3; ++oc) {
                float4 v = acc[j][oc];
                v.x = LEAKY(v.x); v.y = LEAKY(v.y); v.z = LEAKY(v.z); v.w = LEAKY(v.w);
                *(float4*)&buf[oc * CHS + (r0 + j + 3) * STRD + gx1 + 4] = v;
            }
    }
    __syncthreads();

    // conv2: 5 strips (R=2, rows -1..8) x 18 groups = 90 units (exact)
    const bool act2 = tid < 90;
    const int s2 = tid / 18;
    const int gx2 = 4 * (tid - s2 * 18) - 4;
    if (act2) conv_rows<2>(buf, fb + 84, 2 * s2 - 1, gx2, acc);
    __syncthreads();

    if (act2) {
        const int r0 = 2 * s2 - 1;
#pragma unroll
        for (int j = 0; j < 2; ++j)
#pragma unroll
            for (int oc = 0; oc < 3; ++oc) {
                float4 v = acc[j][oc];
                v.x = LEAKY(v.x); v.y = LEAKY(v.y); v.z = LEAKY(v.z); v.w = LEAKY(v.w);
                *(float4*)&buf[oc * CHS + (r0 + j + 3) * STRD + gx2 + 4] = v;
            }
    }
    __syncthreads();

    // conv3: rows 0..7, R=1, all 128 threads
    float4 y[1][3];
    conv_rows<1>(buf, fb + 168, s3, gx3, y);
    float4 y0 = y[0][0], y1 = y[0][1], y2 = y[0][2];
    y0.x = LEAKY(y0.x); y0.y = LEAKY(y0.y); y0.z = LEAKY(y0.z); y0.w = LEAKY(y0.w);
    y1.x = LEAKY(y1.x); y1.y = LEAKY(y1.y); y1.z = LEAKY(y1.z); y1.w = LEAKY(y1.w);
    y2.x = LEAKY(y2.x); y2.y = LEAKY(y2.y); y2.z = LEAKY(y2.z); y2.w = LEAKY(y2.w);

    // ---- 5x conv1x1 chain in registers ----
#pragma unroll
    for (int lay = 0; lay < 5; ++lay) {
        const float* fw = fb + 252 + lay * 12;
        const float w00 = fw[0], w01 = fw[1], w02 = fw[2];
        const float w10 = fw[3], w11 = fw[4], w12 = fw[5];
        const float w20 = fw[6], w21 = fw[7], w22 = fw[8];
        const float c0 = fw[9], c1 = fw[10], c2 = fw[11];
        float4 z0, z1, z2;
        z0.x = fmaf(y0.x, w00, fmaf(y1.x, w01, fmaf(y2.x, w02, c0)));
        z0.y = fmaf(y0.y, w00, fmaf(y1.y, w01, fmaf(y2.y, w02, c0)));
        z0.z = fmaf(y0.z, w00, fmaf(y1.z, w01, fmaf(y2.z, w02, c0)));
        z0.w = fmaf(y0.w, w00, fmaf(y1.w, w01, fmaf(y2.w, w02, c0)));
        z1.x = fmaf(y0.x, w10, fmaf(y1.x, w11, fmaf(y2.x, w12, c1)));
        z1.y = fmaf(y0.y, w10, fmaf(y1.y, w11, fmaf(y2.y, w12, c1)));
        z1.z = fmaf(y0.z, w10, fmaf(y1.z, w11, fmaf(y2.z, w12, c1)));
        z1.w = fmaf(y0.w, w10, fmaf(y1.w, w11, fmaf(y2.w, w12, c1)));
        z2.x = fmaf(y0.x, w20, fmaf(y1.x, w21, fmaf(y2.x, w22, c2)));
        z2.y = fmaf(y0.y, w20, fmaf(y1.y, w21, fmaf(y2.y, w22, c2)));
        z2.z = fmaf(y0.z, w20, fmaf(y1.z, w21, fmaf(y2.z, w22, c2)));
        z2.w = fmaf(y0.w, w20, fmaf(y1.w, w21, fmaf(y2.w, w22, c2)));
        y0.x = LEAKY(z0.x); y0.y = LEAKY(z0.y); y0.z = LEAKY(z0.z); y0.w = LEAKY(z0.w);
        y1.x = LEAKY(z1.x); y1.y = LEAKY(z1.y); y1.z = LEAKY(z1.z); y1.w = LEAKY(z1.w);
        y2.x = LEAKY(z2.x); y2.y = LEAKY(z2.y); y2.z = LEAKY(z2.z); y2.w = LEAKY(z2.w);
    }

    // ---- residual + attention + float4 store (1 row x 4 cols x 3 ch) ----
    const float invH = 1.f / (float)H;
    const float invW = 1.f / (float)W;
    const int gr = trow + s3;
    const float h = (float)gr * invH;
    const float wbase = (float)(tcol + gx3) * invW;
    const float4 wv = make_float4(wbase, wbase + invW, wbase + 2.f * invW, wbase + 3.f * invW);
#pragma unroll
    for (int ch = 0; ch < 3; ++ch) {
        const float* fp = fb + 312 + ch * 16;
        const float pa0 = fp[0], pb0 = fp[1], pc0 = fp[2], pd0 = fp[3];
        const float pa1 = fp[4], pb1 = fp[5], pc1 = fp[6], pd1 = fp[7];
        const float pa2 = fp[8], pb2 = fp[9], pc2 = fp[10], pd2 = fp[11];
        const float pa3 = fp[12], pb3 = fp[13], pc3 = fp[14], pd3 = fp[15];
        const float4 yv = (ch == 0) ? y0 : (ch == 1) ? y1 : y2;
        float4 v;
        v.x = yv.x + res[ch].x;
        v.y = yv.y + res[ch].y;
        v.z = yv.z + res[ch].z;
        v.w = yv.w + res[ch].w;
        const float t0 = fmaf(pa0, h, pd0), t1 = fmaf(pa1, h, pd1);
        const float t2 = fmaf(pa2, h, pd2), t3 = fmaf(pa3, h, pd3);
        float4 o;
        float a0 = fmaf(pb0, wv.x, fmaf(pc0, v.x, t0));
        a0 *= fmaf(pb1, wv.x, fmaf(pc1, v.x, t1));
        a0 *= fmaf(pb2, wv.x, fmaf(pc2, v.x, t2));
        a0 *= fmaf(pb3, wv.x, fmaf(pc3, v.x, t3));
        o.x = v.x * (1.f + a0);
        float a1 = fmaf(pb0, wv.y, fmaf(pc0, v.y, t0));
        a1 *= fmaf(pb1, wv.y, fmaf(pc1, v.y, t1));
        a1 *= fmaf(pb2, wv.y, fmaf(pc2, v.y, t2));
        a1 *= fmaf(pb3, wv.y, fmaf(pc3, v.y, t3));
        o.y = v.y * (1.f + a1);
        float a2 = fmaf(pb0, wv.z, fmaf(pc0, v.z, t0));
        a2 *= fmaf(pb1, wv.z, fmaf(pc1, v.z, t1));
        a2 *= fmaf(pb2, wv.z, fmaf(pc2, v.z, t2));
        a2 *= fmaf(pb3, wv.z, fmaf(pc3, v.z, t3));
        o.z = v.z * (1.f + a2);
        float a3 = fmaf(pb0, wv.w, fmaf(pc0, v.w, t0));
        a3 *= fmaf(pb1, wv.w, fmaf(pc1, v.w, t1));
        a3 *= fmaf(pb2, wv.w, fmaf(pc2, v.w, t2));
        a3 *= fmaf(pb3, wv.w, fmaf(pc3, v.w, t3));
        o.w = v.w * (1.f + a3);
        *(float4*)&dst[((size_t)(b * 3 + ch) * H + gr) * W + tcol + gx3] = o;
    }
}

extern "C" void kernel_launch(void* const* d_in, const int* in_sizes, int n_in,
                              void* d_out, int out_size, void* d_ws, size_t ws_size,
                              hipStream_t stream) {
    const float* x = (const float*)d_in[0];       // (8,3,512,512)
    const float* thumb = (const float*)d_in[1];   // (8,3,64,64)
    const float* Wm = (const float*)d_in[2];      // (3,360)
    const float* bm = (const float*)d_in[3];      // (360,)
    float* out = (float*)d_out;
    float* means = (float*)d_ws;                  // 24 floats
    float* feat = (float*)d_ws + 64;              // (8,360)

    means_kernel<<<24, 256, 0, stream>>>(thumb, means);
    fmm_kernel<<<8, 384, 0, stream>>>(Wm, bm, means, feat);
    // 4096 big-image blocks + 64 thumb blocks
    conv_att_kernel<<<4160, 128, 0, stream>>>(x, thumb, feat, out);
}